// Round 6
// baseline (160.152 us; speedup 1.0000x reference)
//
#include <hip/hip_runtime.h>
#include <hip/hip_bf16.h>
#include <cstddef>

// SpatialConv KERNEL_TYPE=0: 5-tap plus conv, N=16 Ci=Co=256 H=W=64, fp32 I/O.
// 32x32x16 bf16 MFMA; x staged fp32->bf16 in-kernel. Key fix vs R5: all global
// A-loads are issued BEFORE the x-prefetch loads they must outlive, so the
// compiler's auto vmcnt(N) keeps the prefetch in flight (vmcnt is FIFO).
#define N_  16
#define CI  256
#define CO  256
#define KT  5

typedef __attribute__((ext_vector_type(8)))  short  short8;
typedef __attribute__((ext_vector_type(8)))  unsigned short ushort8;
typedef __attribute__((ext_vector_type(4)))  unsigned int uint4v;
typedef __attribute__((ext_vector_type(16))) float  floatx16;

static __device__ __forceinline__ unsigned short f2bf(float f) {
    union { float f; unsigned u; } v; v.f = f;
    unsigned r = v.u + 0x7fff + ((v.u >> 16) & 1);   // RNE
    return (unsigned short)(r >> 16);
}

// ---- prepass: w fp32 [Co][Ci][5] -> wb bf16 [5][Co][Ci] (c contiguous) ----
__global__ void wtrans_kernel(const float* __restrict__ w, unsigned short* __restrict__ wb) {
    int idx = blockIdx.x * 256 + threadIdx.x;
    if (idx >= KT * CO * CI) return;
    int k = idx >> 16;
    int rem = idx & 65535;
    int o = rem >> 8;
    int c = rem & 255;
    wb[idx] = f2bf(w[(size_t)o * (CI * KT) + c * KT + k]);
}

// ---- main: block = 128 o x 256 px (4 h-rows x 64 w); wave = 64 o x 128 px ----
// LDS cell(r, cg, w) = 16B of 8 bf16 channels; slot = r*256 + cg*64 + w.
__global__ __launch_bounds__(256, 2) void conv_mfma(const float* __restrict__ x,
                                                    const unsigned short* __restrict__ wb,
                                                    float* __restrict__ out) {
    __shared__ ushort8 lds[2 * 1536 + 1];   // 2 x 24 KB + zero cell

    const int tid   = threadIdx.x;
    const int bx    = blockIdx.x;
    const int ohalf = bx & 1;
    const int hq    = (bx >> 1) & 15;
    const int n     = bx >> 5;
    const int h0    = hq * 4;
    const int lane  = tid & 63;
    const int wv    = tid >> 6;
    const int l31   = lane & 31;
    const int lh    = lane >> 5;
    const int owave   = ohalf * 128 + (wv & 1) * 64;   // wave o-base (64 wide)
    const int rowbase = (wv >> 1) * 2;                 // wave h-rows: rowbase, rowbase+1

    const int sw  = tid & 63;            // staging: w column
    const int scg = (tid >> 6) & 3;      // staging: c-group of 8

    if (tid == 0) lds[2 * 1536] = (ushort8)0;

    const float* xn = x + (size_t)n * CI * 4096;

    // load 3 staged rows (i0..i0+2) of chunk c into regs (clamped addr, OOB->0 later)
    float xh1[3][8], xh2[3][8];
    auto load_half = [&](int c, int i0, float (&xr)[3][8]) {
        #pragma unroll
        for (int ii = 0; ii < 3; ++ii) {
            int hh  = h0 + (i0 + ii) - 1;
            int hcl = hh < 0 ? 0 : (hh > 63 ? 63 : hh);
            const float* p = xn + (size_t)(c * 32 + scg * 8) * 4096 + hcl * 64 + sw;
            #pragma unroll
            for (int e = 0; e < 8; ++e) xr[ii][e] = p[(size_t)e * 4096];
        }
    };
    auto write_half = [&](int b, int i0, float (&xr)[3][8]) {
        #pragma unroll
        for (int ii = 0; ii < 3; ++ii) {
            int i  = i0 + ii;
            int hh = h0 + i - 1;
            const bool oob = (unsigned)hh >= 64u;   // block-uniform
            uint4v v;
            #pragma unroll
            for (int e = 0; e < 4; ++e) {
                float f0 = oob ? 0.f : xr[ii][2 * e];
                float f1 = oob ? 0.f : xr[ii][2 * e + 1];
                __hip_bfloat162 pk = __float22bfloat162_rn(make_float2(f0, f1));
                union { __hip_bfloat162 h; unsigned u; } cv; cv.h = pk;
                v[e] = cv.u;
            }
            *(uint4v*)&lds[b * 1536 + i * 256 + scg * 64 + sw] = v;
        }
    };

    floatx16 acc[2][4];   // [o-tile][t = hr*2 + wh]
    #pragma unroll
    for (int ot = 0; ot < 2; ++ot)
        #pragma unroll
        for (int t = 0; t < 4; ++t)
            #pragma unroll
            for (int e = 0; e < 16; ++e) acc[ot][t][e] = 0.f;

    const int laneoff = lh * 1024 + l31 * 16;   // lane part of B addr (bytes)
    const char* zcell = (const char*)&lds[2 * 1536];

    // one tap-group MFMA pass: taps [klo, khi)
    auto mfma_taps = [&](const char* bufb, const short8 a[][2][2], int klo, int khi) {
        #pragma unroll
        for (int k = klo; k < khi; ++k) {
            const int dy = (k == 1) ? 0 : (k == 4) ? 2 : 1;
            const int dx = (k == 2) ? 0 : (k == 3) ? 2 : 1;
            #pragma unroll
            for (int ks = 0; ks < 2; ++ks) {
                #pragma unroll
                for (int t = 0; t < 4; ++t) {
                    const int hr = t >> 1, wh = t & 1;
                    const int r  = rowbase + hr + dy;
                    const int wl = wh * 32 + l31 + dx - 1;
                    const char* bp = ((unsigned)wl < 64u)
                        ? bufb + (r * 4096 + ks * 2048 + (wh * 32 + dx - 1) * 16) + laneoff
                        : zcell;
                    const short8 bfrag = *(const short8*)bp;
                    acc[0][t] = __builtin_amdgcn_mfma_f32_32x32x16_bf16(a[k - klo][ks][0], bfrag, acc[0][t], 0, 0, 0);
                    acc[1][t] = __builtin_amdgcn_mfma_f32_32x32x16_bf16(a[k - klo][ks][1], bfrag, acc[1][t], 0, 0, 0);
                }
            }
        }
    };

    // ---- prologue: stage chunk 0 ----
    load_half(0, 0, xh1);
    load_half(0, 3, xh2);
    write_half(0, 0, xh1);
    write_half(0, 3, xh2);
    __syncthreads();

    for (int c = 0; c < 8; ++c) {
        const int cb = c & 1;
        const bool pf = (c < 7);
        const unsigned short* wbase = wb + (size_t)(owave + l31) * 256 + c * 32;
        const char* bufb = (const char*)&lds[cb * 1536];

        // [1] A-frags taps 0-1 (8 x 16B, L2) -- issued BEFORE the x prefetch
        short8 a01[2][2][2];   // [tap][ks][ot]
        #pragma unroll
        for (int k = 0; k < 2; ++k)
            #pragma unroll
            for (int ks = 0; ks < 2; ++ks)
                #pragma unroll
                for (int ot = 0; ot < 2; ++ot)
                    a01[k][ks][ot] = *(const short8*)(wbase + (size_t)k * 65536 + ot * 8192 + ks * 16 + lh * 8);

        // [2] x prefetch half 1 (rows 0-2 of chunk c+1)
        if (pf) load_half(c + 1, 0, xh1);

        // [3] MFMA taps 0-1 (auto vmcnt leaves xh1 in flight)
        mfma_taps(bufb, a01, 0, 2);

        // [4] A-frags taps 2-4 (12 x 16B)
        short8 a234[3][2][2];
        #pragma unroll
        for (int k = 2; k < 5; ++k)
            #pragma unroll
            for (int ks = 0; ks < 2; ++ks)
                #pragma unroll
                for (int ot = 0; ot < 2; ++ot)
                    a234[k - 2][ks][ot] = *(const short8*)(wbase + (size_t)k * 65536 + ot * 8192 + ks * 16 + lh * 8);

        // [5] x prefetch half 2 (rows 3-5 of chunk c+1)
        if (pf) load_half(c + 1, 3, xh2);

        // [6] drain xh1 only (a234/xh2 stay), convert+write into other buffer
        if (pf) write_half(cb ^ 1, 0, xh1);

        // [7] MFMA taps 2-4
        mfma_taps(bufb, a234, 2, 5);

        // [8] drain xh2, write, barrier (nothing left in flight at barrier)
        if (pf) {
            write_half(cb ^ 1, 3, xh2);
            __syncthreads();
        }
    }

    // epilogue: C/D: col(px) = l31, row(o-off) = (reg&3) + 8*(reg>>2) + 4*lh
    #pragma unroll
    for (int ot = 0; ot < 2; ++ot) {
        #pragma unroll
        for (int t = 0; t < 4; ++t) {
            const int hr = t >> 1, wh = t & 1;
            const int h = h0 + rowbase + hr;
            #pragma unroll
            for (int reg = 0; reg < 16; ++reg) {
                int o = owave + ot * 32 + (reg & 3) + 8 * (reg >> 2) + 4 * lh;
                out[(((size_t)n * CO + o) * 64 + h) * 64 + wh * 32 + l31] = acc[ot][t][reg];
            }
        }
    }
}

extern "C" void kernel_launch(void* const* d_in, const int* in_sizes, int n_in,
                              void* d_out, int out_size, void* d_ws, size_t ws_size,
                              hipStream_t stream) {
    const float* x = (const float*)d_in[0];
    const float* w = (const float*)d_in[1];
    float* out = (float*)d_out;

    unsigned short* wb = (unsigned short*)d_ws;    // 640 KB, the only workspace

    wtrans_kernel<<<dim3((KT * CO * CI + 255) / 256), dim3(256), 0, stream>>>(w, wb);
    conv_mfma<<<dim3(N_ * 16 * 2), dim3(256), 0, stream>>>(x, wb, out);
}